// Round 6
// baseline (345.397 us; speedup 1.0000x reference)
//
#include <hip/hip_runtime.h>
#include <hip/hip_bf16.h>
#include <stdint.h>

#define CCH 256

typedef __attribute__((ext_vector_type(8))) short short8;
typedef __attribute__((ext_vector_type(4))) float f32x4;

__device__ __forceinline__ float lrelu(float v) { return v > 0.f ? v : 0.1f * v; }

__device__ __forceinline__ unsigned short f2bf(float f) {
    __hip_bfloat16 h = __float2bfloat16(f);
    return *reinterpret_cast<unsigned short*>(&h);
}

// async global->LDS, 16B per lane; global addr per-lane, LDS dst wave-uniform (+lane*16)
__device__ __forceinline__ void gl_lds16(const void* g, void* s) {
    __builtin_amdgcn_global_load_lds(
        (const __attribute__((address_space(1))) unsigned int*)(uintptr_t)g,
        (__attribute__((address_space(3))) unsigned int*)(unsigned int)(uintptr_t)s,
        16, 0, 0);
}

__device__ __forceinline__ void mem_fence_sched() { asm volatile("" ::: "memory"); }

// compiler memory fence + hw barrier + fence: raw s_barrier that LDS ops can't cross
__device__ __forceinline__ void pipe_barrier() {
    asm volatile("" ::: "memory");
    __builtin_amdgcn_s_barrier();
    asm volatile("" ::: "memory");
}

// NCHW fp32 -> channel-chunked bf16: out[b][kc][y*64+x][32ci].
// grid (8 kc, 64 y, 16 b), block 256.
__global__ __launch_bounds__(256)
void nhwc_k(const float* __restrict__ in, unsigned short* __restrict__ out)
{
    __shared__ float t[32][65];
    const int tid = threadIdx.x;
    const int kc = blockIdx.x, y = blockIdx.y, b = blockIdx.z;
    const float* src = in + ((size_t)(b * 256 + kc * 32)) * 4096 + y * 64;
#pragma unroll
    for (int i = 0; i < 2; ++i) {
        int idx = tid + i * 256;            // 0..511
        int cl = idx >> 4, xg = idx & 15;
        float4 v = *(const float4*)(src + (size_t)cl * 4096 + xg * 4);
        t[cl][xg * 4 + 0] = v.x; t[cl][xg * 4 + 1] = v.y;
        t[cl][xg * 4 + 2] = v.z; t[cl][xg * 4 + 3] = v.w;
    }
    __syncthreads();
    const int x = tid >> 2, cg = tid & 3;
    union { unsigned short us[8]; uint4 v; } u;
#pragma unroll
    for (int j = 0; j < 8; ++j) u.us[j] = f2bf(t[cg * 8 + j][x]);
    unsigned short* dst = out + (((size_t)(b * 8 + kc) * 4096 + y * 64 + x) * 32 + cg * 8);
    *(uint4*)dst = u.v;
}

// w[co][ci][9] fp32 -> wt in FRAGMENT-MAJOR order: wt[ss=kc*9+t][f=0..15][l=0..63][8] bf16
// where lane l of frag f holds co = f*16 + (l&15), ci = kc*32 + (l>>4)*8 + u.
// convmm loads frag f as ONE contiguous 1KiB block (lane*16B linear), global->VGPR.
// grid (72, 2), block 256.
__global__ __launch_bounds__(256)
void wtr_k(const float* __restrict__ w1, const float* __restrict__ w2,
           unsigned short* __restrict__ o1, unsigned short* __restrict__ o2)
{
    const int ss = blockIdx.x;
    const int kc = ss / 9, t = ss - kc * 9;
    const float* w = blockIdx.y ? w2 : w1;
    unsigned short* o = blockIdx.y ? o2 : o1;
#pragma unroll
    for (int rep = 0; rep < 4; ++rep) {
        int slot = threadIdx.x + rep * 256;      // 0..1023: (frag f, lane l)
        int f = slot >> 6, l = slot & 63;
        int co = f * 16 + (l & 15);
        int q  = l >> 4;
        union { unsigned short us[8]; uint4 v; } u;
#pragma unroll
        for (int uu = 0; uu < 8; ++uu)
            u.us[uu] = f2bf(w[((size_t)co * 256 + kc * 32 + q * 8 + uu) * 9 + t]);
        *(uint4*)(o + (size_t)ss * 8192 + slot * 8) = u.v;
    }
}

__global__ __launch_bounds__(256)
void zero_pool_k(float* __restrict__ p) { p[blockIdx.x * 256 + threadIdx.x] = 0.f; }

// Implicit-GEMM 3x3 VALID conv, bf16 MFMA 16x16x32.
// M=Cout=256, N=pixels (block 128), K = 72 stages (kc,tap) x 32.
// Block tile 256x128, 4 waves in 2x2, wave tile 128(m) x 64(n): a[8] x b[4] frags,
// acc 8x4 f32x4. 2 blocks/CU = 2 waves/SIMD.
// R5 was LDS-pipe-bound: 96KB reads + 48KB DMA writes per CU-stage (~1100-1700 cyc)
// vs 1242 cyc MFMA floor. Fix: A (weights, 1.18MB total, same for ALL blocks ->
// L1/L2-resident) goes global->VGPR directly, double-buffered in registers across
// stages (2x-unrolled parity, no v_movs). Only B stays in LDS (gl_lds16, depth-2,
// 3 x 8KB buffers). LDS traffic/CU-stage: 144KB -> 48KB; MFMA pipe becomes binding.
// vmcnt: per iter issue A(s+1)x8 then B(s+2)x2; vmcnt(2) retires {B(s+1), A(s+1)}
// (FIFO: B(s+1) oldest, then A(s+1), B(s+2) newest stays in flight).
// im: [b][kc][WIN*WIN][32] bf16; wt: [ss][16][64][8] bf16 (fragment-major).
// POOL=0: h1 out [b][kc'][NVAL][32] (bias+lrelu, bf16). POOL=1: sum -> atomicAdd pool.
// grid (ceil(NVAL/128), 16 b), block 256, 2 blocks/CU (LDS 24576 B).
template<int POOL, int WIN, int WOUT>
__global__ __launch_bounds__(256, 2)
void convmm_k(const unsigned short* __restrict__ im, const unsigned short* __restrict__ wt,
              const float* __restrict__ bias, unsigned short* __restrict__ outp,
              float* __restrict__ pool)
{
    constexpr int HINPIX = WIN * WIN;
    constexpr int NVAL   = WOUT * WOUT;
    constexpr int NB = 8 * 512;                // B-only buffer: 8 frags x 1KB = 8KB
    __shared__ __align__(16) short Ls[3 * NB]; // 24576 B

    const int tid  = threadIdx.x;
    const int wave = tid >> 6;
    const int lane = tid & 63;
    const int quad = lane >> 4;
    const int l15  = lane & 15;
    const int wm   = (wave & 1) * 128;     // m offset of wave tile (co)
    const int wn   = (wave >> 1) * 64;     // n offset of wave tile (px)
    const int nb0  = blockIdx.x * 128;
    const int b    = blockIdx.y;

    // A: wave needs frags (wave&1)*8 + i (co = wm + i*16 + l15, k-chunk quad).
    const unsigned short* abase = wt + (size_t)((wave & 1) * 8) * 512 + (size_t)lane * 8;
    // B staging: wave stages px-frags 2w, 2w+1; lane l -> px = pfrag*16+(l&15),
    // 16B chunk quad of the px row. Per-lane global src, linear LDS dst.
    size_t bofs[2];
#pragma unroll
    for (int h = 0; h < 2; ++h) {
        int nn = nb0 + (wave * 2 + h) * 16 + l15;
        if (nn > NVAL - 1) nn = NVAL - 1;
        int y = nn / WOUT, x = nn - y * WOUT;
        bofs[h] = ((size_t)(b * 8) * HINPIX + (size_t)y * WIN + x) * 32 + quad * 8;
    }

    f32x4 acc[8][4];
#pragma unroll
    for (int i = 0; i < 8; ++i)
#pragma unroll
        for (int j = 0; j < 4; ++j) { f32x4 z = {0.f, 0.f, 0.f, 0.f}; acc[i][j] = z; }

    short8 aA[8], aB[8];

    // load stage ss's 8 A frags into a register set (8 x global_load_dwordx4, L1/L2-hot)
    auto loadA = [&](int ss, short8* ar) {
        const unsigned short* ap = abase + (size_t)ss * 8192;
#pragma unroll
        for (int i = 0; i < 8; ++i)
            ar[i] = *(const short8*)(ap + i * 512);
    };

    // issue one stage's 2 B gl_lds16 into LDS buffer `buf`
    auto stageB = [&](int ss, short* buf) {
        const int kc = ss / 9, t = ss - kc * 9;
        const int ky = t / 3, kx = t - ky * 3;
        const size_t boff = ((size_t)kc * HINPIX + (size_t)ky * WIN + kx) * 32;
#pragma unroll
        for (int h = 0; h < 2; ++h)
            gl_lds16(im + bofs[h] + boff, buf + (wave * 2 + h) * 512);
    };

    // consume: 4 ds_read_b128 (B frags, 1KB-linear per wave) + 32 MFMA with reg A
    auto compute = [&](const short* buf, const short8* ar) {
        const short* bp = buf + (size_t)(wave >> 1) * 4 * 512 + lane * 8;
        short8 bfr[4];
#pragma unroll
        for (int j = 0; j < 4; ++j)
            bfr[j] = *(const short8*)(bp + j * 512);
        __builtin_amdgcn_s_setprio(1);
#pragma unroll
        for (int i = 0; i < 8; ++i)
#pragma unroll
            for (int j = 0; j < 4; ++j)
                acc[i][j] = __builtin_amdgcn_mfma_f32_16x16x32_bf16(ar[i], bfr[j], acc[i][j], 0, 0, 0);
        __builtin_amdgcn_s_setprio(0);
    };

    short* c0 = Ls;
    short* c1 = Ls + NB;
    short* c2 = Ls + 2 * NB;

    // prologue: A(0) -> aA; B(0), B(1) staged. Retire A(0)+B(0), keep B(1) in flight.
    loadA(0, aA);
    mem_fence_sched();
    stageB(0, c0);
    stageB(1, c1);
    asm volatile("s_waitcnt vmcnt(2)" ::: "memory");
    pipe_barrier();

    // invariant at top of sub-iter s: aX = A(s) (ready), c0 = B(s) (ready),
    // outstanding = B(s+1)'s 2 loads (in flight).
    for (int s = 0; s < 70; s += 2) {
        // even: compute A(s) from aA, prefetch A(s+1) -> aB
        loadA(s + 1, aB);
        mem_fence_sched();
        stageB(s + 2, c2);
        mem_fence_sched();
        compute(c0, aA);
        asm volatile("s_waitcnt vmcnt(2)" ::: "memory");   // retire B(s+1), A(s+1)
        pipe_barrier();
        { short* t = c0; c0 = c1; c1 = c2; c2 = t; }
        // odd: compute A(s+1) from aB, prefetch A(s+2) -> aA
        loadA(s + 2, aA);
        mem_fence_sched();
        stageB(s + 3, c2);
        mem_fence_sched();
        compute(c0, aB);
        asm volatile("s_waitcnt vmcnt(2)" ::: "memory");   // retire B(s+2), A(s+2)
        pipe_barrier();
        { short* t = c0; c0 = c1; c1 = c2; c2 = t; }
    }
    // tail: aA = A(70) ready, c0 = B(70) ready, B(71) in flight
    loadA(71, aB);
    mem_fence_sched();
    compute(c0, aA);                                       // stage 70
    asm volatile("s_waitcnt vmcnt(0)" ::: "memory");
    pipe_barrier();
    compute(c1, aB);                                       // stage 71

    // D layout: col(px)=l15, row(co)=quad*4+reg
    const int co_l = wm + quad * 4;
    if (!POOL) {
#pragma unroll
        for (int i = 0; i < 8; ++i) {
            const int c0i = co_l + i * 16;
            float4 bv = *(const float4*)(bias + c0i);
            unsigned short* dstp = outp + ((size_t)(b * 8 + (c0i >> 5)) * NVAL) * 32 + (c0i & 31);
#pragma unroll
            for (int j = 0; j < 4; ++j) {
                int nn = nb0 + wn + j * 16 + l15;
                if (nn < NVAL) {
                    ushort4 pk = make_ushort4(
                        f2bf(lrelu(acc[i][j].x + bv.x)),
                        f2bf(lrelu(acc[i][j].y + bv.y)),
                        f2bf(lrelu(acc[i][j].z + bv.z)),
                        f2bf(lrelu(acc[i][j].w + bv.w)));
                    *(ushort4*)(dstp + (size_t)nn * 32) = pk;
                }
            }
        }
    } else {
#pragma unroll
        for (int i = 0; i < 8; ++i) {
            const int c0i = co_l + i * 16;
            float4 bv = *(const float4*)(bias + c0i);
            float s0 = 0.f, s1 = 0.f, s2 = 0.f, s3 = 0.f;
#pragma unroll
            for (int j = 0; j < 4; ++j) {
                int nn = nb0 + wn + j * 16 + l15;
                if (nn < NVAL) {
                    s0 += lrelu(acc[i][j].x + bv.x);
                    s1 += lrelu(acc[i][j].y + bv.y);
                    s2 += lrelu(acc[i][j].z + bv.z);
                    s3 += lrelu(acc[i][j].w + bv.w);
                }
            }
#pragma unroll
            for (int off = 1; off < 16; off <<= 1) {
                s0 += __shfl_xor(s0, off, 64);
                s1 += __shfl_xor(s1, off, 64);
                s2 += __shfl_xor(s2, off, 64);
                s3 += __shfl_xor(s3, off, 64);
            }
            if (l15 == 0) {
                float* pp = pool + b * 256 + c0i;
                atomicAdd(pp + 0, s0); atomicAdd(pp + 1, s1);
                atomicAdd(pp + 2, s2); atomicAdd(pp + 3, s3);
            }
        }
    }
}

// kern[b][o] = (1/3600) * sum_c pool[b][c]*w3[o][c] + b3[o]
__global__ __launch_bounds__(256)
void kern_gemm_k(const float* __restrict__ p, const float* __restrict__ w3,
                 const float* __restrict__ b3, float* __restrict__ kern)
{
    const int b = blockIdx.y;
    const int o = blockIdx.x * 256 + threadIdx.x;
    __shared__ float pv[CCH];
    pv[threadIdx.x] = p[b * CCH + threadIdx.x] * (1.f / 3600.f);
    __syncthreads();
    float acc = b3[o];
    const float* wr = w3 + (size_t)o * CCH;
#pragma unroll 4
    for (int c = 0; c < CCH; c += 4) {
        float4 wv = *(const float4*)(wr + c);
        acc += wv.x * pv[c] + wv.y * pv[c + 1] + wv.z * pv[c + 2] + wv.w * pv[c + 3];
    }
    kern[(size_t)b * (9 * CCH) + o] = acc;
}

// Per-sample depthwise 3x3 SAME + bias, fp32, LDS-staged.
// One block (256 thr) per (b,c) plane. LDS tile 66 rows x 67 stride.
// Only the halo ring is zeroed (262 cells); interior rows 1..64 x cols 1..64 are
// fully overwritten by the load phase. Compute reads rows 0..65, cols 0..65.
__global__ __launch_bounds__(256)
void dw_k(const float* __restrict__ x, const float* __restrict__ kern,
          const float* __restrict__ bias, float* __restrict__ out)
{
    __shared__ float t[66 * 67];
    const int tid = threadIdx.x;
    const int bc = blockIdx.x;
    const int c = bc & (CCH - 1);
    const int b = bc >> 8;

    if (tid < 67) { t[tid] = 0.f; t[65 * 67 + tid] = 0.f; }          // rows 0, 65
    if (tid >= 128 && tid < 192) {
        int r = tid - 127;                                            // 1..64
        t[r * 67] = 0.f; t[r * 67 + 65] = 0.f;                        // cols 0, 65
    }

    const float* kp = kern + (size_t)b * (9 * CCH) + c * 9;
    float k[9];
#pragma unroll
    for (int q = 0; q < 9; ++q) k[q] = kp[q];
    const float bs = bias[c];
    const float* xp = x + (size_t)bc * 4096;
    float* op = out + (size_t)bc * 4096;
    __syncthreads();

#pragma unroll
    for (int i = 0; i < 4; ++i) {
        int p4 = tid + i * 256;            // float4 index 0..1023
        float4 v = *(const float4*)(xp + p4 * 4);
        int yy = p4 >> 4, xx = (p4 & 15) * 4;
        float* d = &t[(yy + 1) * 67 + 1 + xx];
        d[0] = v.x; d[1] = v.y; d[2] = v.z; d[3] = v.w;
    }
    __syncthreads();

#pragma unroll
    for (int i = 0; i < 4; ++i) {
        int p4 = tid + i * 256;
        int yy = p4 >> 4, xx = (p4 & 15) * 4;
        float r[3][6];
#pragma unroll
        for (int dy = 0; dy < 3; ++dy)
#pragma unroll
            for (int dx = 0; dx < 6; ++dx)
                r[dy][dx] = t[(yy + dy) * 67 + xx + dx];
        float4 o;
        float* ov = (float*)&o;
#pragma unroll
        for (int j = 0; j < 4; ++j) {
            float a = bs;
#pragma unroll
            for (int dy = 0; dy < 3; ++dy)
#pragma unroll
                for (int dx = 0; dx < 3; ++dx)
                    a += k[dy * 3 + dx] * r[dy][j + dx];
            ov[j] = a;
        }
        *(float4*)(op + p4 * 4) = o;
    }
}

extern "C" void kernel_launch(void* const* d_in, const int* in_sizes, int n_in,
                              void* d_out, int out_size, void* d_ws, size_t ws_size,
                              hipStream_t stream)
{
    const float* x    = (const float*)d_in[0];
    const float* kin  = (const float*)d_in[1];
    const float* w1   = (const float*)d_in[2];
    const float* b1   = (const float*)d_in[3];
    const float* w2   = (const float*)d_in[4];
    const float* b2   = (const float*)d_in[5];
    const float* w3   = (const float*)d_in[6];
    const float* b3   = (const float*)d_in[7];
    const float* bias = (const float*)d_in[8];

    // ws: imA [16][8][4096][32] bf16 | h1 [16][8][3844][32] bf16 (+slack) | w1t | w2t | pool | kern
    unsigned short* imA = (unsigned short*)d_ws;
    unsigned short* h1  = imA + (size_t)16 * 8 * 4096 * 32;
    unsigned short* w1t = h1 + (size_t)16 * 8 * 3844 * 32 + 8192;   // slack for clamped-tap reads
    unsigned short* w2t = w1t + (size_t)72 * 8192;
    float* pool = (float*)(w2t + (size_t)72 * 8192);
    float* kern = pool + 16 * 256;

    float* out = (float*)d_out;

    hipLaunchKernelGGL(zero_pool_k, dim3(16), dim3(256), 0, stream, pool);
    hipLaunchKernelGGL(nhwc_k, dim3(8, 64, 16), dim3(256), 0, stream, kin, imA);
    hipLaunchKernelGGL(wtr_k, dim3(72, 2), dim3(256), 0, stream, w1, w2, w1t, w2t);
    hipLaunchKernelGGL((convmm_k<0, 64, 62>), dim3(31, 16), dim3(256), 0, stream,
                       imA, w1t, b1, h1, (float*)nullptr);
    hipLaunchKernelGGL((convmm_k<1, 62, 60>), dim3(29, 16), dim3(256), 0, stream,
                       h1, w2t, b2, (unsigned short*)nullptr, pool);
    hipLaunchKernelGGL(kern_gemm_k, dim3(9, 16), dim3(256), 0, stream, pool, w3, b3, kern);
    hipLaunchKernelGGL(dw_k, dim3(16 * 256), dim3(256), 0, stream, x, kern, bias, out);
}

// Round 7
// 335.442 us; speedup vs baseline: 1.0297x; 1.0297x over previous
//
#include <hip/hip_runtime.h>
#include <hip/hip_bf16.h>
#include <stdint.h>

#define CCH 256

typedef __attribute__((ext_vector_type(8))) short short8;
typedef __attribute__((ext_vector_type(4))) float f32x4;

__device__ __forceinline__ float lrelu(float v) { return v > 0.f ? v : 0.1f * v; }

__device__ __forceinline__ unsigned short f2bf(float f) {
    __hip_bfloat16 h = __float2bfloat16(f);
    return *reinterpret_cast<unsigned short*>(&h);
}

// async global->LDS, 16B per lane; global addr per-lane, LDS dst wave-uniform (+lane*16)
__device__ __forceinline__ void gl_lds16(const void* g, void* s) {
    __builtin_amdgcn_global_load_lds(
        (const __attribute__((address_space(1))) unsigned int*)(uintptr_t)g,
        (__attribute__((address_space(3))) unsigned int*)(unsigned int)(uintptr_t)s,
        16, 0, 0);
}

__device__ __forceinline__ void mem_fence_sched() { asm volatile("" ::: "memory"); }

// compiler memory fence + hw barrier + fence: raw s_barrier that LDS ops can't cross
__device__ __forceinline__ void pipe_barrier() {
    asm volatile("" ::: "memory");
    __builtin_amdgcn_s_barrier();
    asm volatile("" ::: "memory");
}

// NCHW fp32 -> channel-chunked bf16: out[b][kc][y*64+x][32ci].
// grid (8 kc, 64 y, 16 b), block 256.
__global__ __launch_bounds__(256)
void nhwc_k(const float* __restrict__ in, unsigned short* __restrict__ out)
{
    __shared__ float t[32][65];
    const int tid = threadIdx.x;
    const int kc = blockIdx.x, y = blockIdx.y, b = blockIdx.z;
    const float* src = in + ((size_t)(b * 256 + kc * 32)) * 4096 + y * 64;
#pragma unroll
    for (int i = 0; i < 2; ++i) {
        int idx = tid + i * 256;            // 0..511
        int cl = idx >> 4, xg = idx & 15;
        float4 v = *(const float4*)(src + (size_t)cl * 4096 + xg * 4);
        t[cl][xg * 4 + 0] = v.x; t[cl][xg * 4 + 1] = v.y;
        t[cl][xg * 4 + 2] = v.z; t[cl][xg * 4 + 3] = v.w;
    }
    __syncthreads();
    const int x = tid >> 2, cg = tid & 3;
    union { unsigned short us[8]; uint4 v; } u;
#pragma unroll
    for (int j = 0; j < 8; ++j) u.us[j] = f2bf(t[cg * 8 + j][x]);
    unsigned short* dst = out + (((size_t)(b * 8 + kc) * 4096 + y * 64 + x) * 32 + cg * 8);
    *(uint4*)dst = u.v;
}

// w[co][ci][9] fp32 -> wt in FRAGMENT-MAJOR order: wt[ss=kc*9+t][f=0..15][l=0..63][8] bf16
// where lane l of frag f holds co = f*16 + (l&15), ci = kc*32 + (l>>4)*8 + u.
// convmm stages frag f as ONE contiguous 1KiB block (lane*16B linear) -> zero conflicts.
// grid (72, 2), block 256.
__global__ __launch_bounds__(256)
void wtr_k(const float* __restrict__ w1, const float* __restrict__ w2,
           unsigned short* __restrict__ o1, unsigned short* __restrict__ o2)
{
    const int ss = blockIdx.x;
    const int kc = ss / 9, t = ss - kc * 9;
    const float* w = blockIdx.y ? w2 : w1;
    unsigned short* o = blockIdx.y ? o2 : o1;
#pragma unroll
    for (int rep = 0; rep < 4; ++rep) {
        int slot = threadIdx.x + rep * 256;      // 0..1023: (frag f, lane l)
        int f = slot >> 6, l = slot & 63;
        int co = f * 16 + (l & 15);
        int q  = l >> 4;
        union { unsigned short us[8]; uint4 v; } u;
#pragma unroll
        for (int uu = 0; uu < 8; ++uu)
            u.us[uu] = f2bf(w[((size_t)co * 256 + kc * 32 + q * 8 + uu) * 9 + t]);
        *(uint4*)(o + (size_t)ss * 8192 + slot * 8) = u.v;
    }
}

__global__ __launch_bounds__(256)
void zero_pool_k(float* __restrict__ p) { p[blockIdx.x * 256 + threadIdx.x] = 0.f; }

// Implicit-GEMM 3x3 VALID conv, bf16 MFMA 16x16x32.
// M=Cout=256, N=pixels (block 256), K = 72 stages (kc,tap) x 32.
// Block tile 256x256: 512 threads, 8 waves (2m x 4n), wave tile 128x64 (a[8] x b[4],
// acc 8x4 f32x4). 1 block/CU, 2 waves/SIMD.
// R5 post-mortem: MFMA (1242 cyc) and LDS (1285 cyc) pipes each ~full but NOT
// overlapped (stage = 2290) because each wave's ds_reads feed its own MFMAs inside
// one barrier phase. Fix here (T3/T4): DMA DEPTH-3 over 4 LDS buffers (4 x 32KB =
// 128KB) so stage s+1 is RESIDENT at the top of iter s; each iter prefetches s+1's
// fragments into registers (named sets R0/R1, 2x-unrolled parity) BEFORE the
// register-only MFMAs of stage s -> ds_reads hide under MFMA. Counted vmcnt(4)
// retires s+2, keeps s+3's 4 calls in flight across the barrier (1 barrier/stage).
// A-DMA also halves per tile (16KB shared by the 2x-wide tile).
// im: [b][kc][WIN*WIN][32] bf16; wt: [ss][16][64][8] bf16 (fragment-major).
// POOL=0: h1 out [b][kc'][NVAL][32] (bias+lrelu, bf16). POOL=1: sum -> atomicAdd pool.
// grid (ceil(NVAL/256), 16 b), block 512.
template<int POOL, int WIN, int WOUT>
__global__ __launch_bounds__(512, 1)
void convmm_k(const unsigned short* __restrict__ im, const unsigned short* __restrict__ wt,
              const float* __restrict__ bias, unsigned short* __restrict__ outp,
              float* __restrict__ pool)
{
    constexpr int HINPIX = WIN * WIN;
    constexpr int NVAL   = WOUT * WOUT;
    constexpr int NB = (16 + 16) * 512;        // A 16 frags + B 16 frags, 32KB
    __shared__ __align__(16) short Ls[4 * NB]; // 131072 B

    const int tid  = threadIdx.x;
    const int wave = tid >> 6;                 // 0..7
    const int lane = tid & 63;
    const int quad = lane >> 4;
    const int l15  = lane & 15;
    const int wm   = (wave & 1) * 128;         // m offset of wave tile (co)
    const int wn   = (wave >> 1) * 64;         // n offset of wave tile (px)
    const int nb0  = blockIdx.x * 256;
    const int b    = blockIdx.y;

    // A staging: wave stages frags 2w, 2w+1 (1KB each, linear src+dst)
    const unsigned short* abase = wt + (size_t)(wave * 2) * 512 + (size_t)lane * 8;
    // B staging: wave stages px-frags 2w, 2w+1; lane l -> px = pfrag*16 + (l&15),
    // 16B chunk quad of the px row. Per-lane global src, linear LDS dst.
    size_t bofs[2];
#pragma unroll
    for (int h = 0; h < 2; ++h) {
        int nn = nb0 + (wave * 2 + h) * 16 + l15;
        if (nn > NVAL - 1) nn = NVAL - 1;
        int y = nn / WOUT, x = nn - y * WOUT;
        bofs[h] = ((size_t)(b * 8) * HINPIX + (size_t)y * WIN + x) * 32 + quad * 8;
    }

    f32x4 acc[8][4];
#pragma unroll
    for (int i = 0; i < 8; ++i)
#pragma unroll
        for (int j = 0; j < 4; ++j) { f32x4 z = {0.f, 0.f, 0.f, 0.f}; acc[i][j] = z; }

    // issue one stage's 4 gl_lds16 (2 A + 2 B) into LDS buffer `buf`
    auto stage = [&](int ss, short* buf) {
        const int kc = ss / 9, t = ss - kc * 9;
        const int ky = t / 3, kx = t - ky * 3;
        const size_t aoff = (size_t)ss * 8192;
        const size_t boff = ((size_t)kc * HINPIX + (size_t)ky * WIN + kx) * 32;
        short* bl = buf + 16 * 512;
#pragma unroll
        for (int h = 0; h < 2; ++h)
            gl_lds16(abase + aoff + h * 512, buf + (wave * 2 + h) * 512);
#pragma unroll
        for (int h = 0; h < 2; ++h)
            gl_lds16(im + bofs[h] + boff, bl + (wave * 2 + h) * 512);
    };

    // read this wave's 12 fragments of a RESIDENT buffer into registers
    auto readFrags = [&](const short* buf, short8 (&ar)[8], short8 (&br)[4]) {
        const short* ap = buf + (size_t)(wave & 1) * 8 * 512 + lane * 8;
        const short* bp = buf + 16 * 512 + (size_t)(wave >> 1) * 4 * 512 + lane * 8;
#pragma unroll
        for (int i = 0; i < 8; ++i) ar[i] = *(const short8*)(ap + i * 512);
#pragma unroll
        for (int j = 0; j < 4; ++j) br[j] = *(const short8*)(bp + j * 512);
    };

    // register-only MFMA cluster
    auto compute = [&](const short8 (&ar)[8], const short8 (&br)[4]) {
        __builtin_amdgcn_s_setprio(1);
#pragma unroll
        for (int i = 0; i < 8; ++i)
#pragma unroll
            for (int j = 0; j < 4; ++j)
                acc[i][j] = __builtin_amdgcn_mfma_f32_16x16x32_bf16(ar[i], br[j], acc[i][j], 0, 0, 0);
        __builtin_amdgcn_s_setprio(0);
    };

    short* c0 = Ls;
    short* c1 = Ls + NB;
    short* c2 = Ls + 2 * NB;
    short* c3 = Ls + 3 * NB;
    short8 RA0[8], RB0[4], RA1[8], RB1[4];

    // prologue: stages 0,1,2 in flight (12 calls); retire 0,1; read stage 0 frags.
    stage(0, c0);
    stage(1, c1);
    stage(2, c2);
    asm volatile("s_waitcnt vmcnt(4)" ::: "memory");   // 0,1 landed; 2 in flight
    pipe_barrier();
    readFrags(c0, RA0, RB0);

    // invariant at top of iter s: c0 = s (frags already in cur regs), c1 = s+1
    // (RESIDENT), c2 = s+2 (in flight), c3 = free.
    for (int s = 0; s < 68; s += 2) {
        // even: prefetch s+1 -> R1, stage s+3, compute s from R0
        readFrags(c1, RA1, RB1);
        stage(s + 3, c3);
        mem_fence_sched();
        compute(RA0, RB0);
        asm volatile("s_waitcnt vmcnt(4)" ::: "memory");   // retire s+2, keep s+3
        pipe_barrier();
        { short* t = c0; c0 = c1; c1 = c2; c2 = c3; c3 = t; }
        // odd: prefetch s+2 -> R0, stage s+4, compute s+1 from R1
        readFrags(c1, RA0, RB0);
        stage(s + 4, c3);
        mem_fence_sched();
        compute(RA1, RB1);
        asm volatile("s_waitcnt vmcnt(4)" ::: "memory");   // retire s+3, keep s+4
        pipe_barrier();
        { short* t = c0; c0 = c1; c1 = c2; c2 = c3; c3 = t; }
    }
    // tail: c0 = 68 (R0 loaded), c1 = 69 resident, c2 = 70 in flight
    readFrags(c1, RA1, RB1);                               // 69
    stage(71, c3);
    mem_fence_sched();
    compute(RA0, RB0);                                     // 68
    asm volatile("s_waitcnt vmcnt(4)" ::: "memory");       // retire 70, keep 71
    pipe_barrier();
    { short* t = c0; c0 = c1; c1 = c2; c2 = c3; c3 = t; }  // c0=69,c1=70,c2=71
    readFrags(c1, RA0, RB0);                               // 70
    compute(RA1, RB1);                                     // 69
    asm volatile("s_waitcnt vmcnt(0)" ::: "memory");       // 71 landed
    pipe_barrier();
    readFrags(c2, RA1, RB1);                               // 71
    compute(RA0, RB0);                                     // 70
    compute(RA1, RB1);                                     // 71

    // D layout: col(px)=l15, row(co)=quad*4+reg
    const int co_l = wm + quad * 4;
    if (!POOL) {
#pragma unroll
        for (int i = 0; i < 8; ++i) {
            const int c0i = co_l + i * 16;
            float4 bv = *(const float4*)(bias + c0i);
            unsigned short* dstp = outp + ((size_t)(b * 8 + (c0i >> 5)) * NVAL) * 32 + (c0i & 31);
#pragma unroll
            for (int j = 0; j < 4; ++j) {
                int nn = nb0 + wn + j * 16 + l15;
                if (nn < NVAL) {
                    ushort4 pk = make_ushort4(
                        f2bf(lrelu(acc[i][j].x + bv.x)),
                        f2bf(lrelu(acc[i][j].y + bv.y)),
                        f2bf(lrelu(acc[i][j].z + bv.z)),
                        f2bf(lrelu(acc[i][j].w + bv.w)));
                    *(ushort4*)(dstp + (size_t)nn * 32) = pk;
                }
            }
        }
    } else {
#pragma unroll
        for (int i = 0; i < 8; ++i) {
            const int c0i = co_l + i * 16;
            float4 bv = *(const float4*)(bias + c0i);
            float s0 = 0.f, s1 = 0.f, s2 = 0.f, s3 = 0.f;
#pragma unroll
            for (int j = 0; j < 4; ++j) {
                int nn = nb0 + wn + j * 16 + l15;
                if (nn < NVAL) {
                    s0 += lrelu(acc[i][j].x + bv.x);
                    s1 += lrelu(acc[i][j].y + bv.y);
                    s2 += lrelu(acc[i][j].z + bv.z);
                    s3 += lrelu(acc[i][j].w + bv.w);
                }
            }
#pragma unroll
            for (int off = 1; off < 16; off <<= 1) {
                s0 += __shfl_xor(s0, off, 64);
                s1 += __shfl_xor(s1, off, 64);
                s2 += __shfl_xor(s2, off, 64);
                s3 += __shfl_xor(s3, off, 64);
            }
            if (l15 == 0) {
                float* pp = pool + b * 256 + c0i;
                atomicAdd(pp + 0, s0); atomicAdd(pp + 1, s1);
                atomicAdd(pp + 2, s2); atomicAdd(pp + 3, s3);
            }
        }
    }
}

// kern[b][o] = (1/3600) * sum_c pool[b][c]*w3[o][c] + b3[o]
__global__ __launch_bounds__(256)
void kern_gemm_k(const float* __restrict__ p, const float* __restrict__ w3,
                 const float* __restrict__ b3, float* __restrict__ kern)
{
    const int b = blockIdx.y;
    const int o = blockIdx.x * 256 + threadIdx.x;
    __shared__ float pv[CCH];
    pv[threadIdx.x] = p[b * CCH + threadIdx.x] * (1.f / 3600.f);
    __syncthreads();
    float acc = b3[o];
    const float* wr = w3 + (size_t)o * CCH;
#pragma unroll 4
    for (int c = 0; c < CCH; c += 4) {
        float4 wv = *(const float4*)(wr + c);
        acc += wv.x * pv[c] + wv.y * pv[c + 1] + wv.z * pv[c + 2] + wv.w * pv[c + 3];
    }
    kern[(size_t)b * (9 * CCH) + o] = acc;
}

// Per-sample depthwise 3x3 SAME + bias, fp32, LDS-staged.
// One block (256 thr) per (b,c) plane. LDS tile 66 rows x 67 stride.
// Only the halo ring is zeroed; interior is fully overwritten by the load phase.
__global__ __launch_bounds__(256)
void dw_k(const float* __restrict__ x, const float* __restrict__ kern,
          const float* __restrict__ bias, float* __restrict__ out)
{
    __shared__ float t[66 * 67];
    const int tid = threadIdx.x;
    const int bc = blockIdx.x;
    const int c = bc & (CCH - 1);
    const int b = bc >> 8;

    if (tid < 67) { t[tid] = 0.f; t[65 * 67 + tid] = 0.f; }          // rows 0, 65
    if (tid >= 128 && tid < 192) {
        int r = tid - 127;                                            // 1..64
        t[r * 67] = 0.f; t[r * 67 + 65] = 0.f;                        // cols 0, 65
    }

    const float* kp = kern + (size_t)b * (9 * CCH) + c * 9;
    float k[9];
#pragma unroll
    for (int q = 0; q < 9; ++q) k[q] = kp[q];
    const float bs = bias[c];
    const float* xp = x + (size_t)bc * 4096;
    float* op = out + (size_t)bc * 4096;
    __syncthreads();

#pragma unroll
    for (int i = 0; i < 4; ++i) {
        int p4 = tid + i * 256;            // float4 index 0..1023
        float4 v = *(const float4*)(xp + p4 * 4);
        int yy = p4 >> 4, xx = (p4 & 15) * 4;
        float* d = &t[(yy + 1) * 67 + 1 + xx];
        d[0] = v.x; d[1] = v.y; d[2] = v.z; d[3] = v.w;
    }
    __syncthreads();

#pragma unroll
    for (int i = 0; i < 4; ++i) {
        int p4 = tid + i * 256;
        int yy = p4 >> 4, xx = (p4 & 15) * 4;
        float r[3][6];
#pragma unroll
        for (int dy = 0; dy < 3; ++dy)
#pragma unroll
            for (int dx = 0; dx < 6; ++dx)
                r[dy][dx] = t[(yy + dy) * 67 + xx + dx];
        float4 o;
        float* ov = (float*)&o;
#pragma unroll
        for (int j = 0; j < 4; ++j) {
            float a = bs;
#pragma unroll
            for (int dy = 0; dy < 3; ++dy)
#pragma unroll
                for (int dx = 0; dx < 3; ++dx)
                    a += k[dy * 3 + dx] * r[dy][j + dx];
            ov[j] = a;
        }
        *(float4*)(op + p4 * 4) = o;
    }
}

extern "C" void kernel_launch(void* const* d_in, const int* in_sizes, int n_in,
                              void* d_out, int out_size, void* d_ws, size_t ws_size,
                              hipStream_t stream)
{
    const float* x    = (const float*)d_in[0];
    const float* kin  = (const float*)d_in[1];
    const float* w1   = (const float*)d_in[2];
    const float* b1   = (const float*)d_in[3];
    const float* w2   = (const float*)d_in[4];
    const float* b2   = (const float*)d_in[5];
    const float* w3   = (const float*)d_in[6];
    const float* b3   = (const float*)d_in[7];
    const float* bias = (const float*)d_in[8];

    // ws: imA [16][8][4096][32] bf16 | h1 [16][8][3844][32] bf16 (+slack) | w1t | w2t | pool | kern
    unsigned short* imA = (unsigned short*)d_ws;
    unsigned short* h1  = imA + (size_t)16 * 8 * 4096 * 32;
    unsigned short* w1t = h1 + (size_t)16 * 8 * 3844 * 32 + 8192;   // slack for clamped-tap reads
    unsigned short* w2t = w1t + (size_t)72 * 8192;
    float* pool = (float*)(w2t + (size_t)72 * 8192);
    float* kern = pool + 16 * 256;

    float* out = (float*)d_out;

    hipLaunchKernelGGL(zero_pool_k, dim3(16), dim3(256), 0, stream, pool);
    hipLaunchKernelGGL(nhwc_k, dim3(8, 64, 16), dim3(256), 0, stream, kin, imA);
    hipLaunchKernelGGL(wtr_k, dim3(72, 2), dim3(256), 0, stream, w1, w2, w1t, w2t);
    hipLaunchKernelGGL((convmm_k<0, 64, 62>), dim3(16, 16), dim3(512), 0, stream,
                       imA, w1t, b1, h1, (float*)nullptr);
    hipLaunchKernelGGL((convmm_k<1, 62, 60>), dim3(15, 16), dim3(512), 0, stream,
                       h1, w2t, b2, (unsigned short*)nullptr, pool);
    hipLaunchKernelGGL(kern_gemm_k, dim3(9, 16), dim3(256), 0, stream, pool, w3, b3, kern);
    hipLaunchKernelGGL(dw_k, dim3(16 * 256), dim3(256), 0, stream, x, kern, bias, out);
}

// Round 9
// 334.293 us; speedup vs baseline: 1.0332x; 1.0034x over previous
//
#include <hip/hip_runtime.h>
#include <hip/hip_bf16.h>
#include <stdint.h>

#define CCH 256

typedef __attribute__((ext_vector_type(8))) short short8;
typedef __attribute__((ext_vector_type(4))) float f32x4;

__device__ __forceinline__ float lrelu(float v) { return v > 0.f ? v : 0.1f * v; }

__device__ __forceinline__ unsigned short f2bf(float f) {
    __hip_bfloat16 h = __float2bfloat16(f);
    return *reinterpret_cast<unsigned short*>(&h);
}

// async global->LDS, 16B per lane; global addr per-lane, LDS dst wave-uniform (+lane*16)
__device__ __forceinline__ void gl_lds16(const void* g, void* s) {
    __builtin_amdgcn_global_load_lds(
        (const __attribute__((address_space(1))) unsigned int*)(uintptr_t)g,
        (__attribute__((address_space(3))) unsigned int*)(unsigned int)(uintptr_t)s,
        16, 0, 0);
}

__device__ __forceinline__ void mem_fence_sched() { asm volatile("" ::: "memory"); }

// compiler memory fence + hw barrier + fence: raw s_barrier that LDS ops can't cross
__device__ __forceinline__ void pipe_barrier() {
    asm volatile("" ::: "memory");
    __builtin_amdgcn_s_barrier();
    asm volatile("" ::: "memory");
}

// NCHW fp32 -> channel-chunked bf16: out[b][kc][y*64+x][32ci].
// grid (8 kc, 64 y, 16 b), block 256.
__global__ __launch_bounds__(256)
void nhwc_k(const float* __restrict__ in, unsigned short* __restrict__ out)
{
    __shared__ float t[32][65];
    const int tid = threadIdx.x;
    const int kc = blockIdx.x, y = blockIdx.y, b = blockIdx.z;
    const float* src = in + ((size_t)(b * 256 + kc * 32)) * 4096 + y * 64;
#pragma unroll
    for (int i = 0; i < 2; ++i) {
        int idx = tid + i * 256;            // 0..511
        int cl = idx >> 4, xg = idx & 15;
        float4 v = *(const float4*)(src + (size_t)cl * 4096 + xg * 4);
        t[cl][xg * 4 + 0] = v.x; t[cl][xg * 4 + 1] = v.y;
        t[cl][xg * 4 + 2] = v.z; t[cl][xg * 4 + 3] = v.w;
    }
    __syncthreads();
    const int x = tid >> 2, cg = tid & 3;
    union { unsigned short us[8]; uint4 v; } u;
#pragma unroll
    for (int j = 0; j < 8; ++j) u.us[j] = f2bf(t[cg * 8 + j][x]);
    unsigned short* dst = out + (((size_t)(b * 8 + kc) * 4096 + y * 64 + x) * 32 + cg * 8);
    *(uint4*)dst = u.v;
}

// w[co][ci][9] fp32 -> wt in FRAGMENT-MAJOR order: wt[ss=kc*9+t][f=0..15][l=0..63][8] bf16
// where lane l of frag f holds co = f*16 + (l&15), ci = kc*32 + (l>>4)*8 + u.
// convmm stages frag f as ONE contiguous 1KiB block (lane*16B linear) -> zero conflicts.
// grid (72, 3): y=0 -> w1, y=1 -> w2, y=2 -> zero pool (blocks 0..15).
__global__ __launch_bounds__(256)
void wtr_k(const float* __restrict__ w1, const float* __restrict__ w2,
           unsigned short* __restrict__ o1, unsigned short* __restrict__ o2,
           float* __restrict__ pool)
{
    if (blockIdx.y == 2) {
        if (blockIdx.x < 16) pool[blockIdx.x * 256 + threadIdx.x] = 0.f;
        return;
    }
    const int ss = blockIdx.x;
    const int kc = ss / 9, t = ss - kc * 9;
    const float* w = blockIdx.y ? w2 : w1;
    unsigned short* o = blockIdx.y ? o2 : o1;
#pragma unroll
    for (int rep = 0; rep < 4; ++rep) {
        int slot = threadIdx.x + rep * 256;      // 0..1023: (frag f, lane l)
        int f = slot >> 6, l = slot & 63;
        int co = f * 16 + (l & 15);
        int q  = l >> 4;
        union { unsigned short us[8]; uint4 v; } u;
#pragma unroll
        for (int uu = 0; uu < 8; ++uu)
            u.us[uu] = f2bf(w[((size_t)co * 256 + kc * 32 + q * 8 + uu) * 9 + t]);
        *(uint4*)(o + (size_t)ss * 8192 + slot * 8) = u.v;
    }
}

// Implicit-GEMM 3x3 VALID conv, bf16 MFMA 16x16x32.
// M=Cout=256, N=pixels (block 256), K = 72 stages (kc,tap) x 32.
// Block tile 256x256: 512 threads, 8 waves (2m x 4n), wave tile 128x64 (a[8] x b[4],
// acc 8x4 f32x4). 1 block/CU, 2 waves/SIMD. DMA depth-3 over 4 x 32KB LDS buffers.
// R7 post-mortem: reads-before-MFMA program order serialized the LDS and MFMA
// windows (stage = 1242 + 1130 additive). This round: MFMA CLUSTER FIRST (operands
// in regs from last iter), then sched_barrier(0) pins the boundary, THEN issue
// s+1's ds_reads + s+3's DMA. A wave's reads issue while the co-wave's MFMAs hold
// the matrix pipe; the lgkmcnt wait for the reads lands after the next barrier.
// Counted vmcnt(4) retires s+2, keeps s+3 in flight across the barrier.
// im: [b][kc][WIN*WIN][32] bf16; wt: [ss][16][64][8] bf16 (fragment-major).
// POOL=0: h1 out [b][kc'][NVAL][32] (bias+lrelu, bf16). POOL=1: sum -> atomicAdd pool.
// grid (ceil(NVAL/256), 16 b), block 512.
template<int POOL, int WIN, int WOUT>
__global__ __launch_bounds__(512, 1)
void convmm_k(const unsigned short* __restrict__ im, const unsigned short* __restrict__ wt,
              const float* __restrict__ bias, unsigned short* __restrict__ outp,
              float* __restrict__ pool)
{
    constexpr int HINPIX = WIN * WIN;
    constexpr int NVAL   = WOUT * WOUT;
    constexpr int NB = (16 + 16) * 512;        // A 16 frags + B 16 frags, 32KB
    __shared__ __align__(16) short Ls[4 * NB]; // 131072 B

    const int tid  = threadIdx.x;
    const int wave = tid >> 6;                 // 0..7
    const int lane = tid & 63;
    const int quad = lane >> 4;
    const int l15  = lane & 15;
    const int wm   = (wave & 1) * 128;         // m offset of wave tile (co)
    const int wn   = (wave >> 1) * 64;         // n offset of wave tile (px)
    const int nb0  = blockIdx.x * 256;
    const int b    = blockIdx.y;

    // A staging: wave stages frags 2w, 2w+1 (1KB each, linear src+dst)
    const unsigned short* abase = wt + (size_t)(wave * 2) * 512 + (size_t)lane * 8;
    // B staging: wave stages px-frags 2w, 2w+1; lane l -> px = pfrag*16 + (l&15),
    // 16B chunk quad of the px row. Per-lane global src, linear LDS dst.
    size_t bofs[2];
#pragma unroll
    for (int h = 0; h < 2; ++h) {
        int nn = nb0 + (wave * 2 + h) * 16 + l15;
        if (nn > NVAL - 1) nn = NVAL - 1;
        int y = nn / WOUT, x = nn - y * WOUT;
        bofs[h] = ((size_t)(b * 8) * HINPIX + (size_t)y * WIN + x) * 32 + quad * 8;
    }

    f32x4 acc[8][4];
#pragma unroll
    for (int i = 0; i < 8; ++i)
#pragma unroll
        for (int j = 0; j < 4; ++j) { f32x4 z = {0.f, 0.f, 0.f, 0.f}; acc[i][j] = z; }

    // issue one stage's 4 gl_lds16 (2 A + 2 B) into LDS buffer `buf`
    auto stage = [&](int ss, short* buf) {
        const int kc = ss / 9, t = ss - kc * 9;
        const int ky = t / 3, kx = t - ky * 3;
        const size_t aoff = (size_t)ss * 8192;
        const size_t boff = ((size_t)kc * HINPIX + (size_t)ky * WIN + kx) * 32;
        short* bl = buf + 16 * 512;
#pragma unroll
        for (int h = 0; h < 2; ++h)
            gl_lds16(abase + aoff + h * 512, buf + (wave * 2 + h) * 512);
#pragma unroll
        for (int h = 0; h < 2; ++h)
            gl_lds16(im + bofs[h] + boff, bl + (wave * 2 + h) * 512);
    };

    // read this wave's 12 fragments of a RESIDENT buffer into registers
    auto readFrags = [&](const short* buf, short8 (&ar)[8], short8 (&br)[4]) {
        const short* ap = buf + (size_t)(wave & 1) * 8 * 512 + lane * 8;
        const short* bp = buf + 16 * 512 + (size_t)(wave >> 1) * 4 * 512 + lane * 8;
#pragma unroll
        for (int i = 0; i < 8; ++i) ar[i] = *(const short8*)(ap + i * 512);
#pragma unroll
        for (int j = 0; j < 4; ++j) br[j] = *(const short8*)(bp + j * 512);
    };

    // register-only MFMA cluster; sched_barrier(0) pins the cluster boundary so
    // the following ds_reads cannot be hoisted before the MFMAs.
    auto compute = [&](const short8 (&ar)[8], const short8 (&br)[4]) {
        __builtin_amdgcn_s_setprio(1);
#pragma unroll
        for (int i = 0; i < 8; ++i)
#pragma unroll
            for (int j = 0; j < 4; ++j)
                acc[i][j] = __builtin_amdgcn_mfma_f32_16x16x32_bf16(ar[i], br[j], acc[i][j], 0, 0, 0);
        __builtin_amdgcn_s_setprio(0);
        __builtin_amdgcn_sched_barrier(0);
    };

    short* c0 = Ls;
    short* c1 = Ls + NB;
    short* c2 = Ls + 2 * NB;
    short* c3 = Ls + 3 * NB;
    short8 RA0[8], RB0[4], RA1[8], RB1[4];

    // prologue: stages 0,1,2 in flight (12 calls); retire 0,1; read stage 0 frags.
    stage(0, c0);
    stage(1, c1);
    stage(2, c2);
    asm volatile("s_waitcnt vmcnt(4)" ::: "memory");   // 0,1 landed; 2 in flight
    pipe_barrier();
    readFrags(c0, RA0, RB0);

    // invariant at top of iter s: R_cur = s frags (ready), c1 = s+1 (RESIDENT),
    // c2 = s+2 (in flight), c3 = free.
    for (int s = 0; s < 68; s += 2) {
        // even: compute s from R0 FIRST, then prefetch s+1 -> R1, stage s+3
        compute(RA0, RB0);
        readFrags(c1, RA1, RB1);
        stage(s + 3, c3);
        asm volatile("s_waitcnt vmcnt(4)" ::: "memory");   // retire s+2, keep s+3
        pipe_barrier();
        { short* t = c0; c0 = c1; c1 = c2; c2 = c3; c3 = t; }
        // odd: compute s+1 from R1, prefetch s+2 -> R0, stage s+4
        compute(RA1, RB1);
        readFrags(c1, RA0, RB0);
        stage(s + 4, c3);
        asm volatile("s_waitcnt vmcnt(4)" ::: "memory");   // retire s+3, keep s+4
        pipe_barrier();
        { short* t = c0; c0 = c1; c1 = c2; c2 = c3; c3 = t; }
    }
    // tail: R0 = 68 ready, c1 = 69 resident, c2 = 70 in flight
    compute(RA0, RB0);                                     // 68
    readFrags(c1, RA1, RB1);                               // 69
    stage(71, c3);
    asm volatile("s_waitcnt vmcnt(4)" ::: "memory");       // retire 70, keep 71
    pipe_barrier();
    { short* t = c0; c0 = c1; c1 = c2; c2 = c3; c3 = t; }  // c0=69,c1=70,c2=71
    compute(RA1, RB1);                                     // 69
    readFrags(c1, RA0, RB0);                               // 70
    asm volatile("s_waitcnt vmcnt(0)" ::: "memory");       // 71 landed
    pipe_barrier();
    compute(RA0, RB0);                                     // 70
    readFrags(c2, RA1, RB1);                               // 71
    compute(RA1, RB1);                                     // 71

    // D layout: col(px)=l15, row(co)=quad*4+reg
    const int co_l = wm + quad * 4;
    if (!POOL) {
#pragma unroll
        for (int i = 0; i < 8; ++i) {
            const int c0i = co_l + i * 16;
            float4 bv = *(const float4*)(bias + c0i);
            unsigned short* dstp = outp + ((size_t)(b * 8 + (c0i >> 5)) * NVAL) * 32 + (c0i & 31);
#pragma unroll
            for (int j = 0; j < 4; ++j) {
                int nn = nb0 + wn + j * 16 + l15;
                if (nn < NVAL) {
                    ushort4 pk = make_ushort4(
                        f2bf(lrelu(acc[i][j].x + bv.x)),
                        f2bf(lrelu(acc[i][j].y + bv.y)),
                        f2bf(lrelu(acc[i][j].z + bv.z)),
                        f2bf(lrelu(acc[i][j].w + bv.w)));
                    *(ushort4*)(dstp + (size_t)nn * 32) = pk;
                }
            }
        }
    } else {
#pragma unroll
        for (int i = 0; i < 8; ++i) {
            const int c0i = co_l + i * 16;
            float4 bv = *(const float4*)(bias + c0i);
            float s0 = 0.f, s1 = 0.f, s2 = 0.f, s3 = 0.f;
#pragma unroll
            for (int j = 0; j < 4; ++j) {
                int nn = nb0 + wn + j * 16 + l15;
                if (nn < NVAL) {
                    s0 += lrelu(acc[i][j].x + bv.x);
                    s1 += lrelu(acc[i][j].y + bv.y);
                    s2 += lrelu(acc[i][j].z + bv.z);
                    s3 += lrelu(acc[i][j].w + bv.w);
                }
            }
#pragma unroll
            for (int off = 1; off < 16; off <<= 1) {
                s0 += __shfl_xor(s0, off, 64);
                s1 += __shfl_xor(s1, off, 64);
                s2 += __shfl_xor(s2, off, 64);
                s3 += __shfl_xor(s3, off, 64);
            }
            if (l15 == 0) {
                float* pp = pool + b * 256 + c0i;
                atomicAdd(pp + 0, s0); atomicAdd(pp + 1, s1);
                atomicAdd(pp + 2, s2); atomicAdd(pp + 3, s3);
            }
        }
    }
}

// kern[b][o] = (1/3600) * sum_c pool[b][c]*w3[o][c] + b3[o]
__global__ __launch_bounds__(256)
void kern_gemm_k(const float* __restrict__ p, const float* __restrict__ w3,
                 const float* __restrict__ b3, float* __restrict__ kern)
{
    const int b = blockIdx.y;
    const int o = blockIdx.x * 256 + threadIdx.x;
    __shared__ float pv[CCH];
    pv[threadIdx.x] = p[b * CCH + threadIdx.x] * (1.f / 3600.f);
    __syncthreads();
    float acc = b3[o];
    const float* wr = w3 + (size_t)o * CCH;
#pragma unroll 4
    for (int c = 0; c < CCH; c += 4) {
        float4 wv = *(const float4*)(wr + c);
        acc += wv.x * pv[c] + wv.y * pv[c + 1] + wv.z * pv[c + 2] + wv.w * pv[c + 3];
    }
    kern[(size_t)b * (9 * CCH) + o] = acc;
}

// Per-sample depthwise 3x3 SAME + bias, fp32, LDS-staged.
// One block (256 thr) per (b,c) plane. LDS tile 66 rows x 67 stride.
// Only the halo ring is zeroed; interior is fully overwritten by the load phase.
__global__ __launch_bounds__(256)
void dw_k(const float* __restrict__ x, const float* __restrict__ kern,
          const float* __restrict__ bias, float* __restrict__ out)
{
    __shared__ float t[66 * 67];
    const int tid = threadIdx.x;
    const int bc = blockIdx.x;
    const int c = bc & (CCH - 1);
    const int b = bc >> 8;

    if (tid < 67) { t[tid] = 0.f; t[65 * 67 + tid] = 0.f; }          // rows 0, 65
    if (tid >= 128 && tid < 192) {
        int r = tid - 127;                                            // 1..64
        t[r * 67] = 0.f; t[r * 67 + 65] = 0.f;                        // cols 0, 65
    }

    const float* kp = kern + (size_t)b * (9 * CCH) + c * 9;
    float k[9];
#pragma unroll
    for (int q = 0; q < 9; ++q) k[q] = kp[q];
    const float bs = bias[c];
    const float* xp = x + (size_t)bc * 4096;
    float* op = out + (size_t)bc * 4096;
    __syncthreads();

#pragma unroll
    for (int i = 0; i < 4; ++i) {
        int p4 = tid + i * 256;            // float4 index 0..1023
        float4 v = *(const float4*)(xp + p4 * 4);
        int yy = p4 >> 4, xx = (p4 & 15) * 4;
        float* d = &t[(yy + 1) * 67 + 1 + xx];
        d[0] = v.x; d[1] = v.y; d[2] = v.z; d[3] = v.w;
    }
    __syncthreads();

#pragma unroll
    for (int i = 0; i < 4; ++i) {
        int p4 = tid + i * 256;
        int yy = p4 >> 4, xx = (p4 & 15) * 4;
        float r[3][6];
#pragma unroll
        for (int dy = 0; dy < 3; ++dy)
#pragma unroll
            for (int dx = 0; dx < 6; ++dx)
                r[dy][dx] = t[(yy + dy) * 67 + xx + dx];
        float4 o;
        float* ov = (float*)&o;
#pragma unroll
        for (int j = 0; j < 4; ++j) {
            float a = bs;
#pragma unroll
            for (int dy = 0; dy < 3; ++dy)
#pragma unroll
                for (int dx = 0; dx < 3; ++dx)
                    a += k[dy * 3 + dx] * r[dy][j + dx];
            ov[j] = a;
        }
        *(float4*)(op + p4 * 4) = o;
    }
}

extern "C" void kernel_launch(void* const* d_in, const int* in_sizes, int n_in,
                              void* d_out, int out_size, void* d_ws, size_t ws_size,
                              hipStream_t stream)
{
    const float* x    = (const float*)d_in[0];
    const float* kin  = (const float*)d_in[1];
    const float* w1   = (const float*)d_in[2];
    const float* b1   = (const float*)d_in[3];
    const float* w2   = (const float*)d_in[4];
    const float* b2   = (const float*)d_in[5];
    const float* w3   = (const float*)d_in[6];
    const float* b3   = (const float*)d_in[7];
    const float* bias = (const float*)d_in[8];

    // ws: imA [16][8][4096][32] bf16 | h1 [16][8][3844][32] bf16 (+slack) | w1t | w2t | pool | kern
    unsigned short* imA = (unsigned short*)d_ws;
    unsigned short* h1  = imA + (size_t)16 * 8 * 4096 * 32;
    unsigned short* w1t = h1 + (size_t)16 * 8 * 3844 * 32 + 8192;   // slack for clamped-tap reads
    unsigned short* w2t = w1t + (size_t)72 * 8192;
    float* pool = (float*)(w2t + (size_t)72 * 8192);
    float* kern = pool + 16 * 256;

    float* out = (float*)d_out;

    hipLaunchKernelGGL(nhwc_k, dim3(8, 64, 16), dim3(256), 0, stream, kin, imA);
    hipLaunchKernelGGL(wtr_k, dim3(72, 3), dim3(256), 0, stream, w1, w2, w1t, w2t, pool);
    hipLaunchKernelGGL((convmm_k<0, 64, 62>), dim3(16, 16), dim3(512), 0, stream,
                       imA, w1t, b1, h1, (float*)nullptr);
    hipLaunchKernelGGL((convmm_k<1, 62, 60>), dim3(15, 16), dim3(512), 0, stream,
                       h1, w2t, b2, (unsigned short*)nullptr, pool);
    hipLaunchKernelGGL(kern_gemm_k, dim3(9, 16), dim3(256), 0, stream, pool, w3, b3, kern);
    hipLaunchKernelGGL(dw_k, dim3(16 * 256), dim3(256), 0, stream, x, kern, bias, out);
}